// Round 3
// baseline (301.442 us; speedup 1.0000x reference)
//
#include <hip/hip_runtime.h>

// GroupLinearBlock: out = einsum('nhd,hdf', (rmsnorm_h(x@W) + b)/sqrt2, K)
// Counted-vmcnt pipelined GEMM1 (BM=128,BN=128,BK=64; A reg-staged f32->bf16
// with T2 XOR swizzle; B via global_load_lds from pre-blocked layout; raw
// s_barrier + s_waitcnt vmcnt(8) so A-loads span barriers), fused per-wave
// RMSNorm + bias-blend + GEMM2 epilogue.

typedef __attribute__((ext_vector_type(8))) __bf16 bf16x8;
typedef __attribute__((ext_vector_type(4))) float f32x4;
typedef __attribute__((ext_vector_type(2))) unsigned int uint2v;
typedef __attribute__((ext_vector_type(8))) unsigned short ushort8;

__device__ __forceinline__ unsigned short f2bf(float f) {
  unsigned int u = __builtin_bit_cast(unsigned int, f);
  u += 0x7FFFu + ((u >> 16) & 1u);
  return (unsigned short)(u >> 16);
}

__device__ __forceinline__ f32x4 mfma_bf16(bf16x8 a, bf16x8 b, f32x4 c) {
  return __builtin_amdgcn_mfma_f32_16x16x32_bf16(a, b, c, 0, 0, 0);
}

__device__ __forceinline__ void gl_lds16(const void* g, void* l) {
  __builtin_amdgcn_global_load_lds(
      (const __attribute__((address_space(1))) unsigned int*)g,
      (__attribute__((address_space(3))) unsigned int*)l, 16, 0, 0);
}

// ---- prep: w_lin [k=1024][n=1024] f32 -> wb2[ct(8)][kt(16)][kc(8)][col(128)][8] bf16
// kc = ks*4+lg; k = kt*64 + (kc>>2)*32 + (kc&3)*8 + j. Flat-copy staging layout.
__global__ void prep_w2(const float* __restrict__ w, unsigned short* __restrict__ wb) {
  const int kt = blockIdx.x, ct = blockIdx.y, col = threadIdx.x;   // 128 thr
  #pragma unroll
  for (int kc = 0; kc < 8; ++kc) {
    ushort8 v;
    #pragma unroll
    for (int j = 0; j < 8; ++j) {
      const int k = kt * 64 + (kc >> 2) * 32 + (kc & 3) * 8 + j;
      v[j] = f2bf(w[(size_t)k * 1024 + ct * 128 + col]);
    }
    *reinterpret_cast<ushort8*>(wb + ((((size_t)ct * 16 + kt) * 8 + kc) * 128 + col) * 8) = v;
  }
}

// ---- prep: kernel [16][d=64][f=64] f32 -> kt [16][f][d] bf16 ----
__global__ void transpose_k(const float* __restrict__ kin, unsigned short* __restrict__ kt) {
  __shared__ float tile[64][65];
  const int h = blockIdx.x;
  const int t = threadIdx.x;                       // 256
  #pragma unroll
  for (int i = 0; i < 16; ++i) {
    int idx = i * 256 + t;
    tile[idx >> 6][idx & 63] = kin[(size_t)h * 4096 + idx];
  }
  __syncthreads();
  #pragma unroll
  for (int i = 0; i < 16; ++i) {
    int idx = i * 256 + t;
    kt[(size_t)h * 4096 + idx] = f2bf(tile[idx & 63][idx >> 6]);
  }
}

// ---- main: 4096 blocks x 256 threads; tile 128x128, K=1024, BK=64 ----
__global__ __launch_bounds__(256, 2)
void fused_main(const float* __restrict__ x,
                const float* __restrict__ nbias,
                const unsigned short* __restrict__ wb,
                const unsigned short* __restrict__ ktg,
                float* __restrict__ out)
{
  // LDS: Abuf0 [0,16K) Abuf1 [16K,32K) bf16 128x64 XOR-swizzled;
  //      Bbuf0 [32K,48K) Bbuf1 [48K,64K) bf16 [kc 8][col 128][8].
  // Epilogue reuses [0,32K) as per-wave y (64x64 bf16, XOR-swizzled).
  __shared__ __align__(16) unsigned char smem[65536];
  const int tid = threadIdx.x;
  const int wv = tid >> 6, lane = tid & 63, l15 = lane & 15, lg = lane >> 4;
  const int wr = wv >> 1, wc = wv & 1;           // wave tile: rows wr*64, cols wc*64
  const int bid = blockIdx.x;
  const int gx = bid & 7, slot = bid >> 3;       // XCD swizzle: 8 ct-blocks of one
  const int rt = ((slot >> 3) << 3) + gx;        // rt run consecutively per XCD
  const int ct = slot & 7;
  const size_t row0 = (size_t)rt * 128;

  const float* xb = x + row0 * 1024;
  const unsigned char* wsrc = reinterpret_cast<const unsigned char*>(wb) + (size_t)ct * 262144;

  // A-staging thread mapping: thread -> (row group ar_, 16B chunk ac_)
  const int ar_ = tid >> 4, ac_ = tid & 15;
  const float* agp = xb + (size_t)ar_ * 1024 + ac_ * 4;
  const int aw_off = (ac_ * 8) ^ ((ar_ & 7) << 4);          // swizzled write offset

  // fragment-read bases
  const int abase = (wr * 64 + l15) * 128;
  const int aswz  = (l15 & 7) << 4;
  const int ofs0  = (lg * 16) ^ aswz;                        // ks=0
  const int ofs1  = (64 + lg * 16) ^ aswz;                   // ks=1
  const int bcol  = (wc * 64 + l15) * 16 + lg * 2048;

  f32x4 acc[4][4];
  const f32x4 z4 = {0.f, 0.f, 0.f, 0.f};
  #pragma unroll
  for (int mi = 0; mi < 4; ++mi)
    #pragma unroll
    for (int ni = 0; ni < 4; ++ni) acc[mi][ni] = z4;

  f32x4 arg[2][8];   // two in-flight A register sets (statically indexed)

  auto stageB = [&](int t, int bsel) {
    unsigned char* Bb = smem + 32768 + (bsel << 14);
    #pragma unroll
    for (int it = 0; it < 4; ++it) {
      const int L = it * 4096 + tid * 16;
      gl_lds16(wsrc + (size_t)t * 16384 + L, Bb + L);        // flat copy
    }
  };
  auto loadA = [&](int t, f32x4* dst) {
    #pragma unroll
    for (int j = 0; j < 8; ++j)
      dst[j] = *reinterpret_cast<const f32x4*>(agp + j * 16384 + t * 64);
  };
  auto cvtwrA = [&](const f32x4* src, int bsel) {
    unsigned char* Ab = smem + (bsel << 14);
    #pragma unroll
    for (int j = 0; j < 8; ++j) {
      const f32x4 v = src[j];
      unsigned int lo = ((unsigned)__builtin_bit_cast(unsigned short, (__bf16)v[0])) |
                        ((unsigned)__builtin_bit_cast(unsigned short, (__bf16)v[1]) << 16);
      unsigned int hi = ((unsigned)__builtin_bit_cast(unsigned short, (__bf16)v[2])) |
                        ((unsigned)__builtin_bit_cast(unsigned short, (__bf16)v[3]) << 16);
      uint2v p; p[0] = lo; p[1] = hi;
      *reinterpret_cast<uint2v*>(Ab + j * 2048 + ar_ * 128 + aw_off) = p;
    }
  };
  auto phase = [&](int csel, int ks) {
    const unsigned char* Ab = smem + (csel << 14);
    const unsigned char* Bb = smem + 32768 + (csel << 14);
    const int aofs = ks ? ofs1 : ofs0;
    bf16x8 af[4], bq[4];
    #pragma unroll
    for (int mi = 0; mi < 4; ++mi)
      af[mi] = *reinterpret_cast<const bf16x8*>(Ab + abase + mi * 2048 + aofs);
    #pragma unroll
    for (int ni = 0; ni < 4; ++ni)
      bq[ni] = *reinterpret_cast<const bf16x8*>(Bb + (ks << 13) + bcol + ni * 256);
    #pragma unroll
    for (int mi = 0; mi < 4; ++mi)
      #pragma unroll
      for (int ni = 0; ni < 4; ++ni)
        acc[mi][ni] = mfma_bf16(af[mi], bq[ni], acc[mi][ni]);
  };

  // ---- prologue: B(0) -> Bbuf0; A(0),A(1) -> regs; A(0) -> Abuf0 ----
  stageB(0, 0);
  __builtin_amdgcn_sched_barrier(0);
  loadA(0, arg[0]);
  loadA(1, arg[1]);
  __builtin_amdgcn_sched_barrier(0);
  cvtwrA(arg[0], 0);          // auto vmcnt waits through A(0) => B(0) done too
  asm volatile("s_waitcnt lgkmcnt(0)" ::: "memory");
  __builtin_amdgcn_sched_barrier(0);
  __builtin_amdgcn_s_barrier();
  __builtin_amdgcn_sched_barrier(0);

  // ---- main loop: 16 K-tiles, counted-vmcnt pipeline ----
  #pragma unroll
  for (int t = 0; t < 16; ++t) {
    const int c = t & 1, n = c ^ 1;
    if (t + 1 < 16) stageB(t + 1, n);            // 4 gl_lds (oldest in queue)
    __builtin_amdgcn_sched_barrier(0);
    if (t + 2 < 16) loadA(t + 2, arg[c]);        // 8 vmem, stay in flight across barrier
    __builtin_amdgcn_sched_barrier(0);

    phase(c, 0);                                  // 8 ds_read + 16 MFMA
    if (t + 1 < 16) cvtwrA(arg[n], n);            // counted auto-wait (A(t+1) only)
    phase(c, 1);                                  // 8 ds_read + 16 MFMA

    if (t + 1 < 16) {
      asm volatile("s_waitcnt lgkmcnt(0)" ::: "memory");   // ds_writes visible
      if (t + 2 < 16) asm volatile("s_waitcnt vmcnt(8)" ::: "memory");  // B(t+1) done, A(t+2) flies
      else            asm volatile("s_waitcnt vmcnt(0)" ::: "memory");  // tail: nothing else out
      __builtin_amdgcn_sched_barrier(0);
      __builtin_amdgcn_s_barrier();
      __builtin_amdgcn_sched_barrier(0);
    }
  }

  __syncthreads();   // full drain; reuse LDS [0,32K) for y

  // ---- epilogue: per-head RMSNorm + bias blend -> y LDS -> GEMM2 ----
  const int h = ct * 2 + wc;
  unsigned short* yw = reinterpret_cast<unsigned short*>(smem) + wv * 4096;  // 64x64 swz
  const float* bb = nbias + (row0 + wr * 64) * 1024 + (size_t)h * 64 + l15;

  #pragma unroll
  for (int mi = 0; mi < 4; ++mi) {
    float ss[4];
    #pragma unroll
    for (int r = 0; r < 4; ++r) {
      float p = 0.f;
      #pragma unroll
      for (int ni = 0; ni < 4; ++ni) { const float v = acc[mi][ni][r]; p += v * v; }
      ss[r] = p;
    }
    #pragma unroll
    for (int s = 1; s < 16; s <<= 1)
      #pragma unroll
      for (int r = 0; r < 4; ++r) ss[r] += __shfl_xor(ss[r], s, 64);
    #pragma unroll
    for (int r = 0; r < 4; ++r) {
      const float rs = rsqrtf(ss[r] * 0.015625f + 1e-6f);
      const int rl = mi * 16 + lg * 4 + r;
      const float* bp = bb + (size_t)rl * 1024;
      #pragma unroll
      for (int ni = 0; ni < 4; ++ni) {
        const float y = (acc[mi][ni][r] * rs + bp[ni * 16]) * 0.70710678118654752f;
        const __bf16 yb = (__bf16)y;
        yw[rl * 64 + ((ni * 16 + l15) ^ ((rl & 7) << 3))] = __builtin_bit_cast(unsigned short, yb);
      }
    }
  }

  // GEMM2: y[64][64] @ ktg[h][f][d]
  const unsigned short* ktp = ktg + (size_t)h * 4096;
  bf16x8 b2[4][2];
  #pragma unroll
  for (int ff = 0; ff < 4; ++ff)
    #pragma unroll
    for (int ks = 0; ks < 2; ++ks)
      b2[ff][ks] = *reinterpret_cast<const bf16x8*>(ktp + (ff * 16 + l15) * 64 + ks * 32 + 8 * lg);

  #pragma unroll
  for (int m2 = 0; m2 < 4; ++m2) {
    f32x4 a2[4] = {z4, z4, z4, z4};
    const int row = m2 * 16 + l15;
    #pragma unroll
    for (int ks = 0; ks < 2; ++ks) {
      bf16x8 a = *reinterpret_cast<const bf16x8*>(
          yw + row * 64 + ((ks * 32 + lg * 8) ^ ((row & 7) << 3)));
      #pragma unroll
      for (int ff = 0; ff < 4; ++ff) a2[ff] = mfma_bf16(a, b2[ff][ks], a2[ff]);
    }
    float* ob = out + (row0 + wr * 64 + m2 * 16 + lg * 4) * 1024 + ct * 128 + wc * 64 + l15;
    #pragma unroll
    for (int ff = 0; ff < 4; ++ff)
      #pragma unroll
      for (int r = 0; r < 4; ++r)
        ob[(size_t)r * 1024 + ff * 16] = a2[ff][r];
  }
}

extern "C" void kernel_launch(void* const* d_in, const int* in_sizes, int n_in,
                              void* d_out, int out_size, void* d_ws, size_t ws_size,
                              hipStream_t stream) {
  const float* x  = (const float*)d_in[0];   // [65536][1024]
  const float* nb = (const float*)d_in[1];   // [65536][16][64]
  const float* wl = (const float*)d_in[2];   // [1024][1024]
  const float* kr = (const float*)d_in[3];   // [16][64][64]
  float* out = (float*)d_out;

  unsigned short* wbp = (unsigned short*)d_ws;           // 2 MB blocked W
  unsigned short* ktp = wbp + 1024 * 1024;               // 128 KB

  hipLaunchKernelGGL(prep_w2, dim3(16, 8), dim3(128), 0, stream, wl, wbp);
  hipLaunchKernelGGL(transpose_k, dim3(16), dim3(256), 0, stream, kr, ktp);
  hipLaunchKernelGGL(fused_main, dim3(4096), dim3(256), 0, stream, x, nb, wbp, ktp, out);
}